// Round 6
// baseline (307.969 us; speedup 1.0000x reference)
//
#include <hip/hip_runtime.h>
#include <math.h>

// Problem constants: B=2, L=2048, E=1024, H=16, D=64
#define LQ 2048
#define EQ 1024
#define M_ROWS 4096
#define BH 32

typedef _Float16 f16x8 __attribute__((ext_vector_type(8)));
typedef _Float16 f16x4 __attribute__((ext_vector_type(4)));
typedef float f32x4 __attribute__((ext_vector_type(4)));
typedef float f32x16 __attribute__((ext_vector_type(16)));

// q pre-scale: 1/sqrt(64) * log2(e)  -> softmax in exp2 domain
#define QSCALE 0.1803368801111204f

__device__ __forceinline__ void async_ld16(const _Float16* g, _Float16* l) {
  __builtin_amdgcn_global_load_lds(
      (const __attribute__((address_space(1))) unsigned int*)g,
      (__attribute__((address_space(3))) unsigned int*)l, 16, 0, 0);
}

// ---------------------------------------------------------------------------
// Convert xt, xs (fp32) -> fp16.
// ---------------------------------------------------------------------------
__global__ __launch_bounds__(256) void convert_x(
    const float* __restrict__ xt, const float* __restrict__ xs,
    _Float16* __restrict__ xt16, _Float16* __restrict__ xs16) {
  int i = blockIdx.x * 256 + threadIdx.x;
  const float* s; _Float16* d; size_t off;
  if (i < 524288) { s = xt; d = xt16; off = (size_t)i * 8; }
  else            { s = xs; d = xs16; off = (size_t)(i - 524288) * 8; }
  float4 a = *(const float4*)&s[off];
  float4 b = *(const float4*)&s[off + 4];
  f16x8 h;
  h[0] = (_Float16)a.x; h[1] = (_Float16)a.y; h[2] = (_Float16)a.z; h[3] = (_Float16)a.w;
  h[4] = (_Float16)b.x; h[5] = (_Float16)b.y; h[6] = (_Float16)b.z; h[7] = (_Float16)b.w;
  *(f16x8*)&d[off] = h;
}

// ---------------------------------------------------------------------------
// Transpose+convert weights: W[k][n] fp32 -> WT[n][k] fp16.
// ---------------------------------------------------------------------------
__global__ __launch_bounds__(256) void transpose_w(
    const float* __restrict__ Wt, const float* __restrict__ Ws,
    const float* __restrict__ Wc,
    _Float16* __restrict__ WtT, _Float16* __restrict__ WsT,
    _Float16* __restrict__ WcT) {
  __shared__ float T[32][33];
  int tx = threadIdx.x & 31, ty = threadIdx.x >> 5;
  int c0 = blockIdx.x * 32;
  int k0 = blockIdx.y * 32;
  const float* W; _Float16* D; int Nw, cl;
  if (c0 < 3072)      { W = Wt; D = WtT; Nw = 3072; cl = c0; }
  else if (c0 < 5120) { W = Ws; D = WsT; Nw = 2048; cl = c0 - 3072; }
  else                { W = Wc; D = WcT; Nw = 1024; cl = c0 - 5120; }
#pragma unroll
  for (int j = 0; j < 4; ++j)
    T[ty + j * 8][tx] = W[(size_t)(k0 + ty + j * 8) * Nw + cl + tx];
  __syncthreads();
#pragma unroll
  for (int j = 0; j < 4; ++j)
    D[(size_t)(cl + ty + j * 8) * 1024 + k0 + tx] = (_Float16)T[tx][ty + j * 8];
}

// ---------------------------------------------------------------------------
// fp16 MFMA GEMM (m97 recipe). Modes:
//  0: grid (16, 48).
//     by<32: QK t-branch: C = xt16 @ WtT[0:2048]^T; scatter q (QSCALE) / kt.
//     by>=32: V^T path: A=WtT rows 2048+, B=xt16 batch b -> C[dim][seq],
//       stored CONTIGUOUS along seq into vT[bh][d][l]. (No scatter.)
//  1: s-proj QK + fused key combine (reads kt from mode 0):
//       k1 = kt + lts*ks -> kcat[:,0:64], k2 = lst*kt+lss*ks -> [:,64:128].
//  2: plain fp32 out (c_proj).
// ---------------------------------------------------------------------------
__global__ __launch_bounds__(256) void gemm_bt(
    const _Float16* __restrict__ A, const _Float16* __restrict__ Bm,
    const float* __restrict__ bias,
    float* __restrict__ outf, _Float16* __restrict__ q16,
    _Float16* __restrict__ k16, _Float16* __restrict__ v16,
    const float* __restrict__ lam_ts, const float* __restrict__ lam_st,
    const float* __restrict__ lam_ss,
    int mode) {
  __shared__ _Float16 Al[128 * 32];
  __shared__ _Float16 Bl[128 * 32];

  const int tid = threadIdx.x;
  const int w = tid >> 6;
  const int lane = tid & 63;
  const int quad = lane >> 4;
  const int l15 = lane & 15;
  const int wm = w >> 1, wn = w & 1;

  const _Float16* Ab = A;
  const _Float16* Bb = Bm;
  int m0 = blockIdx.y * 128;
  const int n0 = blockIdx.x * 128;
  int bsel = 0;
  bool vpath = false;
  if (mode == 0 && blockIdx.y >= 32) {
    int by2 = blockIdx.y - 32;              // 0..15
    bsel = by2 >> 3;                        // batch
    m0 = (by2 & 7) * 128;                   // dim-rows 0..1023
    Ab = Bm + (size_t)2048 * 1024;          // WtT V-rows
    Bb = A + (size_t)bsel * 2048 * 1024;    // xt16 batch b
    vpath = true;
  }

  const int srow = lane >> 2;
  const int schunk = ((lane & 3) ^ ((lane >> 3) & 3)) * 8;

  float lts = 0.f, lst = 0.f, lss = 0.f;
  if (mode == 1) { lts = lam_ts[0]; lst = lam_st[0]; lss = lam_ss[0]; }

  f32x4 acc[4][4];
#pragma unroll
  for (int mb = 0; mb < 4; ++mb)
#pragma unroll
    for (int nb = 0; nb < 4; ++nb) acc[mb][nb] = (f32x4){0.f, 0.f, 0.f, 0.f};

  const int key = (l15 >> 1) & 3;

  for (int kt = 0; kt < 1024; kt += 32) {
    __syncthreads();
#pragma unroll
    for (int i = 0; i < 2; ++i) {
      int rt = w * 32 + i * 16;
      async_ld16(&Ab[(size_t)(m0 + rt + srow) * 1024 + kt + schunk], &Al[rt * 32]);
      async_ld16(&Bb[(size_t)(n0 + rt + srow) * 1024 + kt + schunk], &Bl[rt * 32]);
    }
    __syncthreads();

    f16x8 af[4], bf[4];
    const int pc = (quad ^ key) * 8;
#pragma unroll
    for (int mb = 0; mb < 4; ++mb)
      af[mb] = *(f16x8*)&Al[(wm * 64 + mb * 16 + l15) * 32 + pc];
#pragma unroll
    for (int nb = 0; nb < 4; ++nb)
      bf[nb] = *(f16x8*)&Bl[(wn * 64 + nb * 16 + l15) * 32 + pc];
#pragma unroll
    for (int mb = 0; mb < 4; ++mb)
#pragma unroll
      for (int nb = 0; nb < 4; ++nb)
        acc[mb][nb] = __builtin_amdgcn_mfma_f32_16x16x32_f16(af[mb], bf[nb], acc[mb][nb], 0, 0, 0);
  }

#pragma unroll
  for (int mb = 0; mb < 4; ++mb)
#pragma unroll
    for (int nb = 0; nb < 4; ++nb)
#pragma unroll
      for (int r = 0; r < 4; ++r) {
        int row = m0 + wm * 64 + mb * 16 + quad * 4 + r;
        int col = n0 + wn * 64 + nb * 16 + l15;
        if (vpath) {
          // row = dim index 0..1023 (h*64+dd), col = seq pos; contiguous store
          float val = acc[mb][nb][r] + bias[2048 + row];
          v16[(size_t)(bsel * 1024 + row) * 2048 + col] = (_Float16)val;
        } else {
          float val = acc[mb][nb][r] + bias[col];
          if (mode == 2) {
            outf[(size_t)row * 1024 + col] = val;
          } else {
            int bb = row >> 11, ll = row & 2047;
            int which = col >> 10, e = col & 1023;
            int hh = e >> 6, dd = e & 63;
            size_t rowhd = (size_t)(bb * 16 + hh) * 2048 + ll;
            if (mode == 0) {
              if (which == 0) q16[rowhd * 128 + dd] = (_Float16)(val * QSCALE);
              else            k16[rowhd * 128 + dd] = (_Float16)val;
            } else {
              if (which == 0) {
                q16[rowhd * 128 + 64 + dd] = (_Float16)(val * QSCALE);
              } else {
                float ktv = (float)k16[rowhd * 128 + dd];   // written by mode 0
                float ksv = val;
                k16[rowhd * 128 + dd]      = (_Float16)(ktv + lts * ksv);
                k16[rowhd * 128 + 64 + dd] = (_Float16)(lst * ktv + lss * ksv);
              }
            }
          }
        }
      }
}

// ---------------------------------------------------------------------------
// MFMA flash attention v4: 32x32x16 MFMA, O^T formulation, DOUBLE-BUFFERED
// K/V DMA. Next tile's global_load_lds issues right after the barrier and
// lands while the current tile computes -> the next barrier's vmcnt drain is
// nearly free. LDS: 2*(16K + 8K) + 18K = 67.6 KB -> 2 blocks/CU.
// ---------------------------------------------------------------------------
__global__ __launch_bounds__(256, 2) void flash_attn_mfma(
    const _Float16* __restrict__ qcat, const _Float16* __restrict__ kcat,
    const _Float16* __restrict__ vT, _Float16* __restrict__ y) {
  const int bh = blockIdx.y;
  const int qt0 = blockIdx.x * 128;
  const int b = bh >> 4, h = bh & 15;
  const _Float16* Qg = qcat + (size_t)bh * LQ * 128;
  const _Float16* Kg = kcat + (size_t)bh * LQ * 128;
  const _Float16* Vg = vT + (size_t)bh * 64 * LQ;     // [dim][key]

  __shared__ _Float16 Ksh0[64 * 128];
  __shared__ _Float16 Ksh1[64 * 128];
  __shared__ _Float16 Vsh0[64 * 64];
  __shared__ _Float16 Vsh1[64 * 64];
  __shared__ _Float16 Psh[4 * 32 * 72];

  const int tid = threadIdx.x;
  const int w = tid >> 6;                    // wave 0..3
  const int lane = tid & 63;
  const int half = lane >> 5;                // 0/1
  const int l31 = lane & 31;

  // Q B-frags resident: wave w owns qrows qt0 + w*32 + [0,32)
  f16x8 qf[8];
#pragma unroll
  for (int db = 0; db < 8; ++db)
    qf[db] = *(const f16x8*)&Qg[(size_t)(qt0 + w * 32 + l31) * 128 + db * 16 + half * 8];

  float m_i = -INFINITY;
  float l_i = 0.f;
  f32x16 O[2];
#pragma unroll
  for (int nt = 0; nt < 2; ++nt)
#pragma unroll
    for (int r = 0; r < 16; ++r) O[nt][r] = 0.f;

  _Float16* Pw = &Psh[w * 32 * 72];

  auto dma = [&](int t, _Float16* Kd, _Float16* Vd) {
#pragma unroll
    for (int a = 0; a < 4; ++a) {
      int row = w * 16 + a * 4 + (lane >> 4);
      int sc = (lane & 15) ^ (row & 7);
      async_ld16(&Kg[(size_t)(t + row) * 128 + sc * 8], &Kd[(w * 16 + a * 4) * 128]);
    }
#pragma unroll
    for (int a = 0; a < 2; ++a) {
      int row = w * 16 + a * 8 + (lane >> 3);          // dim
      int sc = (lane & 7) ^ (row & 7);
      async_ld16(&Vg[(size_t)row * LQ + t + sc * 8], &Vd[(w * 16 + a * 8) * 64]);
    }
  };

  auto compute = [&](const _Float16* Ks, const _Float16* Vs) {
    // S^T[key][qrow]: 2 key-tiles of 32, contraction over 128 dims
    f32x16 S[2];
#pragma unroll
    for (int kb = 0; kb < 2; ++kb)
#pragma unroll
      for (int r = 0; r < 16; ++r) S[kb][r] = 0.f;
#pragma unroll
    for (int db = 0; db < 8; ++db) {
      const int pc = ((db * 2 + half) ^ (lane & 7)) * 8;
      f16x8 af[2];
#pragma unroll
      for (int kb = 0; kb < 2; ++kb)
        af[kb] = *(const f16x8*)&Ks[(kb * 32 + l31) * 128 + pc];
#pragma unroll
      for (int kb = 0; kb < 2; ++kb)
        S[kb] = __builtin_amdgcn_mfma_f32_32x32x16_f16(af[kb], qf[db], S[kb], 0, 0, 0);
    }

    // Online softmax (exp2 domain), lane-local qrow = l31.
    float mx = -INFINITY;
#pragma unroll
    for (int kb = 0; kb < 2; ++kb)
#pragma unroll
      for (int r = 0; r < 16; ++r) mx = fmaxf(mx, S[kb][r]);
    mx = fmaxf(mx, __shfl_xor(mx, 32));
    float m_new = fmaxf(m_i, mx);
    float alpha = __builtin_amdgcn_exp2f(m_i - m_new);
    float s = 0.f;
#pragma unroll
    for (int kb = 0; kb < 2; ++kb)
#pragma unroll
      for (int r = 0; r < 16; ++r) {
        float p = __builtin_amdgcn_exp2f(S[kb][r] - m_new);
        S[kb][r] = p;
        s += p;
      }
    s += __shfl_xor(s, 32);
    l_i = l_i * alpha + s;
    m_i = m_new;

    // P^T -> LDS as Psh[qrow][key]
#pragma unroll
    for (int kb = 0; kb < 2; ++kb)
#pragma unroll
      for (int rg = 0; rg < 4; ++rg) {
        f16x4 p4;
#pragma unroll
        for (int i = 0; i < 4; ++i) p4[i] = (_Float16)S[kb][rg * 4 + i];
        *(f16x4*)&Pw[l31 * 72 + kb * 32 + rg * 8 + half * 4] = p4;
      }

    // Rescale O (lane-local alpha)
#pragma unroll
    for (int nt = 0; nt < 2; ++nt)
#pragma unroll
      for (int r = 0; r < 16; ++r) O[nt][r] *= alpha;

    // O^T += mfma(A=V^T, B=P^T): contraction over 64 keys
#pragma unroll
    for (int kb = 0; kb < 4; ++kb) {
      f16x8 pb = *(const f16x8*)&Pw[l31 * 72 + kb * 16 + half * 8];
      f16x8 av[2];
#pragma unroll
      for (int nt = 0; nt < 2; ++nt) {
        int dim = nt * 32 + l31;
        int pc = ((kb * 2 + half) ^ (dim & 7)) * 8;
        av[nt] = *(const f16x8*)&Vs[dim * 64 + pc];
      }
#pragma unroll
      for (int nt = 0; nt < 2; ++nt)
        O[nt] = __builtin_amdgcn_mfma_f32_32x32x16_f16(av[nt], pb, O[nt], 0, 0, 0);
    }
  };

  dma(0, Ksh0, Vsh0);
  for (int t = 0; t < LQ; t += 128) {
    __syncthreads();                 // drains DMA(t) + protects buffers
    dma(t + 64, Ksh1, Vsh1);         // overlaps with compute(t)
    compute(Ksh0, Vsh0);
    __syncthreads();                 // drains DMA(t+64)
    if (t + 128 < LQ) dma(t + 128, Ksh0, Vsh0);
    compute(Ksh1, Vsh1);
  }

  // Epilogue: lane-local 1/l; O^T row = dim, col = qrow (lane-local).
  float inv = 1.f / l_i;
  int qrow = qt0 + w * 32 + l31;
#pragma unroll
  for (int nt = 0; nt < 2; ++nt)
#pragma unroll
    for (int rg = 0; rg < 4; ++rg) {
      f16x4 o4;
#pragma unroll
      for (int i = 0; i < 4; ++i) o4[i] = (_Float16)(O[nt][rg * 4 + i] * inv);
      int dim = nt * 32 + rg * 8 + half * 4;
      *(f16x4*)&y[((size_t)b * LQ + qrow) * EQ + h * 64 + dim] = o4;
    }
}

// ---------------------------------------------------------------------------
extern "C" void kernel_launch(void* const* d_in, const int* in_sizes, int n_in,
                              void* d_out, int out_size, void* d_ws, size_t ws_size,
                              hipStream_t stream) {
  const float* xt = (const float*)d_in[0];
  const float* xs = (const float*)d_in[1];
  const float* Wt = (const float*)d_in[2];
  const float* bt = (const float*)d_in[3];
  const float* Ws = (const float*)d_in[4];
  const float* bs = (const float*)d_in[5];
  const float* Wc = (const float*)d_in[6];
  const float* bc = (const float*)d_in[7];
  const float* lam_ts = (const float*)d_in[8];
  const float* lam_st = (const float*)d_in[9];
  const float* lam_ss = (const float*)d_in[10];
  float* out = (float*)d_out;

  _Float16* w16 = (_Float16*)d_ws;
  _Float16* xt16 = w16;                       // 4,194,304
  _Float16* xs16 = xt16 + 4194304;            // 4,194,304
  _Float16* WtT  = xs16 + 4194304;            // 3,145,728
  _Float16* WsT  = WtT + 3145728;             // 2,097,152
  _Float16* WcT  = WsT + 2097152;             // 1,048,576
  _Float16* qcat = WcT + 1048576;             // 8,388,608  [bh][l][128]
  _Float16* kcat = qcat + 8388608;            // 8,388,608  [bh][l][128]
  _Float16* vbufT = kcat + 8388608;           // 4,194,304  [bh][dim][l]
  _Float16* ybuf = vbufT + 4194304;           // 4,194,304  [b*l][1024]

  convert_x<<<4096, 256, 0, stream>>>(xt, xs, xt16, xs16);
  transpose_w<<<dim3(192, 32), 256, 0, stream>>>(Wt, Ws, Wc, WtT, WsT, WcT);
  // mode 0: QK t-branch (by 0..31) + V^T transposed GEMM (by 32..47)
  gemm_bt<<<dim3(16, 48), 256, 0, stream>>>(
      xt16, WtT, bt, nullptr, qcat, kcat, vbufT, nullptr, nullptr, nullptr, 0);
  // mode 1: QK s-branch + fused key combine
  gemm_bt<<<dim3(16, 32), 256, 0, stream>>>(
      xs16, WsT, bs, nullptr, qcat, kcat, nullptr, lam_ts, lam_st, lam_ss, 1);
  flash_attn_mfma<<<dim3(16, 32), 256, 0, stream>>>(qcat, kcat, vbufT, ybuf);
  // mode 2: c_proj
  gemm_bt<<<dim3(8, 32), 256, 0, stream>>>(
      ybuf, WcT, bc, out, nullptr, nullptr, nullptr, nullptr, nullptr, nullptr, 2);
}

// Round 7
// 281.857 us; speedup vs baseline: 1.0926x; 1.0926x over previous
//
#include <hip/hip_runtime.h>
#include <math.h>

// Problem constants: B=2, L=2048, E=1024, H=16, D=64
#define LQ 2048
#define EQ 1024
#define M_ROWS 4096
#define BH 32

typedef _Float16 f16x8 __attribute__((ext_vector_type(8)));
typedef _Float16 f16x4 __attribute__((ext_vector_type(4)));
typedef _Float16 f16x2 __attribute__((ext_vector_type(2)));
typedef float f32x4 __attribute__((ext_vector_type(4)));
typedef float f32x16 __attribute__((ext_vector_type(16)));

// 1/sqrt(64) * log2(e) -> softmax in exp2 domain (applied to combined q)
#define QSCALE 0.1803368801111204f

__device__ __forceinline__ void async_ld16(const _Float16* g, _Float16* l) {
  __builtin_amdgcn_global_load_lds(
      (const __attribute__((address_space(1))) unsigned int*)g,
      (__attribute__((address_space(3))) unsigned int*)l, 16, 0, 0);
}

// ---------------------------------------------------------------------------
// Prep (1 launch): blocks [0,4096) convert xt,xs fp32->fp16;
// blocks [4096,10240) transpose W fp32[k][n] -> WT fp16[n][k].
// ---------------------------------------------------------------------------
__global__ __launch_bounds__(256) void prep(
    const float* __restrict__ xt, const float* __restrict__ xs,
    const float* __restrict__ Wt, const float* __restrict__ Ws,
    const float* __restrict__ Wc,
    _Float16* __restrict__ xt16, _Float16* __restrict__ xs16,
    _Float16* __restrict__ WtT, _Float16* __restrict__ WsT,
    _Float16* __restrict__ WcT) {
  int gb = blockIdx.x;
  if (gb < 4096) {
    int i = gb * 256 + threadIdx.x;
    const float* s; _Float16* d; size_t off;
    if (i < 524288) { s = xt; d = xt16; off = (size_t)i * 8; }
    else            { s = xs; d = xs16; off = (size_t)(i - 524288) * 8; }
    float4 a = *(const float4*)&s[off];
    float4 b = *(const float4*)&s[off + 4];
    f16x8 h;
    h[0] = (_Float16)a.x; h[1] = (_Float16)a.y; h[2] = (_Float16)a.z; h[3] = (_Float16)a.w;
    h[4] = (_Float16)b.x; h[5] = (_Float16)b.y; h[6] = (_Float16)b.z; h[7] = (_Float16)b.w;
    *(f16x8*)&d[off] = h;
  } else {
    __shared__ float T[32][33];
    int tb = gb - 4096;
    int tx = threadIdx.x & 31, ty = threadIdx.x >> 5;
    int c0 = (tb % 192) * 32;
    int k0 = (tb / 192) * 32;
    const float* W; _Float16* D; int Nw, cl;
    if (c0 < 3072)      { W = Wt; D = WtT; Nw = 3072; cl = c0; }
    else if (c0 < 5120) { W = Ws; D = WsT; Nw = 2048; cl = c0 - 3072; }
    else                { W = Wc; D = WcT; Nw = 1024; cl = c0 - 5120; }
#pragma unroll
    for (int j = 0; j < 4; ++j)
      T[ty + j * 8][tx] = W[(size_t)(k0 + ty + j * 8) * Nw + cl + tx];
    __syncthreads();
#pragma unroll
    for (int j = 0; j < 4; ++j)
      D[(size_t)(cl + ty + j * 8) * 1024 + k0 + tx] = (_Float16)T[tx][ty + j * 8];
  }
}

// ---------------------------------------------------------------------------
// Merged projection GEMM (m97 core), ONE launch, grid (16, 80):
//  by in [0,32):  t-QK: xt16 @ WtT[0:2048]^T -> qt->qcat[:,0:64] (raw),
//                 kt->kcat[:,0:64]. No lambda combine (moved to flash).
//  by in [32,48): V^T: WtT[2048:3072] as A, xt16 batch as B -> C[dim][seq]
//                 stored contiguous along seq into vT[bh][d][l].
//  by in [48,80): s-QK: xs16 @ WsT^T -> qs->qcat[:,64:128], ks->kcat[:,64:128].
// All three sub-GEMMs independent -> co-resident, tails overlap.
// ---------------------------------------------------------------------------
__global__ __launch_bounds__(256) void proj_gemm(
    const _Float16* __restrict__ xt16, const _Float16* __restrict__ xs16,
    const _Float16* __restrict__ WtT, const _Float16* __restrict__ WsT,
    const float* __restrict__ bt, const float* __restrict__ bs,
    _Float16* __restrict__ q16, _Float16* __restrict__ k16,
    _Float16* __restrict__ v16) {
  __shared__ _Float16 Al[128 * 32];
  __shared__ _Float16 Bl[128 * 32];

  const int tid = threadIdx.x;
  const int w = tid >> 6;
  const int lane = tid & 63;
  const int quad = lane >> 4;
  const int l15 = lane & 15;
  const int wm = w >> 1, wn = w & 1;
  const int by = blockIdx.y;
  const int n0 = blockIdx.x * 128;

  const _Float16* Ab;
  const _Float16* Bb;
  const float* bias;
  int m0, bsel = 0, branch;
  if (by < 32) {            // t-QK
    branch = 0; Ab = xt16; Bb = WtT; bias = bt; m0 = by * 128;
  } else if (by < 48) {     // V^T
    branch = 1;
    int by2 = by - 32;
    bsel = by2 >> 3;
    m0 = (by2 & 7) * 128;
    Ab = WtT + (size_t)2048 * 1024;
    Bb = xt16 + (size_t)bsel * 2048 * 1024;
    bias = bt;
  } else {                  // s-QK
    branch = 2; Ab = xs16; Bb = WsT; bias = bs; m0 = (by - 48) * 128;
  }

  const int srow = lane >> 2;
  const int schunk = ((lane & 3) ^ ((lane >> 3) & 3)) * 8;

  f32x4 acc[4][4];
#pragma unroll
  for (int mb = 0; mb < 4; ++mb)
#pragma unroll
    for (int nb = 0; nb < 4; ++nb) acc[mb][nb] = (f32x4){0.f, 0.f, 0.f, 0.f};

  const int key = (l15 >> 1) & 3;

  for (int kt = 0; kt < 1024; kt += 32) {
    __syncthreads();
#pragma unroll
    for (int i = 0; i < 2; ++i) {
      int rt = w * 32 + i * 16;
      async_ld16(&Ab[(size_t)(m0 + rt + srow) * 1024 + kt + schunk], &Al[rt * 32]);
      async_ld16(&Bb[(size_t)(n0 + rt + srow) * 1024 + kt + schunk], &Bl[rt * 32]);
    }
    __syncthreads();

    f16x8 af[4], bf[4];
    const int pc = (quad ^ key) * 8;
#pragma unroll
    for (int mb = 0; mb < 4; ++mb)
      af[mb] = *(f16x8*)&Al[(wm * 64 + mb * 16 + l15) * 32 + pc];
#pragma unroll
    for (int nb = 0; nb < 4; ++nb)
      bf[nb] = *(f16x8*)&Bl[(wn * 64 + nb * 16 + l15) * 32 + pc];
#pragma unroll
    for (int mb = 0; mb < 4; ++mb)
#pragma unroll
      for (int nb = 0; nb < 4; ++nb)
        acc[mb][nb] = __builtin_amdgcn_mfma_f32_16x16x32_f16(af[mb], bf[nb], acc[mb][nb], 0, 0, 0);
  }

#pragma unroll
  for (int mb = 0; mb < 4; ++mb)
#pragma unroll
    for (int nb = 0; nb < 4; ++nb)
#pragma unroll
      for (int r = 0; r < 4; ++r) {
        int row = m0 + wm * 64 + mb * 16 + quad * 4 + r;
        int col = n0 + wn * 64 + nb * 16 + l15;
        if (branch == 1) {
          float val = acc[mb][nb][r] + bias[2048 + row];
          v16[(size_t)(bsel * 1024 + row) * 2048 + col] = (_Float16)val;
        } else {
          float val = acc[mb][nb][r] + bias[col];
          int bb = row >> 11, ll = row & 2047;
          int which = col >> 10, e = col & 1023;
          int hh = e >> 6, dd = e & 63;
          size_t rowhd = (size_t)(bb * 16 + hh) * 2048 + ll;
          int off = (branch == 0) ? 0 : 64;    // t fills [0:64], s fills [64:128]
          if (which == 0) q16[rowhd * 128 + off + dd] = (_Float16)val;
          else            k16[rowhd * 128 + off + dd] = (_Float16)val;
        }
      }
}

// ---------------------------------------------------------------------------
// c_proj GEMM (m97 core): out = ybuf @ WcT^T + bc, fp32 out.
// ---------------------------------------------------------------------------
__global__ __launch_bounds__(256) void cproj_gemm(
    const _Float16* __restrict__ A, const _Float16* __restrict__ Bm,
    const float* __restrict__ bias, float* __restrict__ outf) {
  __shared__ _Float16 Al[128 * 32];
  __shared__ _Float16 Bl[128 * 32];

  const int tid = threadIdx.x;
  const int w = tid >> 6;
  const int lane = tid & 63;
  const int quad = lane >> 4;
  const int l15 = lane & 15;
  const int wm = w >> 1, wn = w & 1;
  const int m0 = blockIdx.y * 128;
  const int n0 = blockIdx.x * 128;

  const int srow = lane >> 2;
  const int schunk = ((lane & 3) ^ ((lane >> 3) & 3)) * 8;

  f32x4 acc[4][4];
#pragma unroll
  for (int mb = 0; mb < 4; ++mb)
#pragma unroll
    for (int nb = 0; nb < 4; ++nb) acc[mb][nb] = (f32x4){0.f, 0.f, 0.f, 0.f};

  const int key = (l15 >> 1) & 3;

  for (int kt = 0; kt < 1024; kt += 32) {
    __syncthreads();
#pragma unroll
    for (int i = 0; i < 2; ++i) {
      int rt = w * 32 + i * 16;
      async_ld16(&A[(size_t)(m0 + rt + srow) * 1024 + kt + schunk], &Al[rt * 32]);
      async_ld16(&Bm[(size_t)(n0 + rt + srow) * 1024 + kt + schunk], &Bl[rt * 32]);
    }
    __syncthreads();

    f16x8 af[4], bf[4];
    const int pc = (quad ^ key) * 8;
#pragma unroll
    for (int mb = 0; mb < 4; ++mb)
      af[mb] = *(f16x8*)&Al[(wm * 64 + mb * 16 + l15) * 32 + pc];
#pragma unroll
    for (int nb = 0; nb < 4; ++nb)
      bf[nb] = *(f16x8*)&Bl[(wn * 64 + nb * 16 + l15) * 32 + pc];
#pragma unroll
    for (int mb = 0; mb < 4; ++mb)
#pragma unroll
      for (int nb = 0; nb < 4; ++nb)
        acc[mb][nb] = __builtin_amdgcn_mfma_f32_16x16x32_f16(af[mb], bf[nb], acc[mb][nb], 0, 0, 0);
  }

#pragma unroll
  for (int mb = 0; mb < 4; ++mb)
#pragma unroll
    for (int nb = 0; nb < 4; ++nb)
#pragma unroll
      for (int r = 0; r < 4; ++r) {
        int row = m0 + wm * 64 + mb * 16 + quad * 4 + r;
        int col = n0 + wn * 64 + nb * 16 + l15;
        outf[(size_t)row * 1024 + col] = acc[mb][nb][r] + bias[col];
      }
}

// ---------------------------------------------------------------------------
// MFMA flash attention v5: 32x32x16, O^T form, dbuf K/V DMA, and:
//  - q-combine on load: q1 = QSCALE*(qt + lst*qs), q2 = QSCALE*(lts*qt+lss*qs)
//    against raw kcat = [kt | ks]  (removes GEMM-side dependency).
//  - P LDS round-trip replaced by shfl_xor(32) register exchange: the 32x32
//    C-layout (row=(r&3)+8*(r>>2)+4*half) splits each 8-key B-frag k-group
//    between lane-half partners; exchange packed f16x2 pairs -> PV B-operand
//    in registers. No Psh (LDS 48 KB).
// ---------------------------------------------------------------------------
__global__ __launch_bounds__(256, 2) void flash_attn_mfma(
    const _Float16* __restrict__ qcat, const _Float16* __restrict__ kcat,
    const _Float16* __restrict__ vT, _Float16* __restrict__ y,
    const float* __restrict__ lam_ts, const float* __restrict__ lam_st,
    const float* __restrict__ lam_ss) {
  const int bh = blockIdx.y;
  const int qt0 = blockIdx.x * 128;
  const int b = bh >> 4, h = bh & 15;
  const _Float16* Qg = qcat + (size_t)bh * LQ * 128;
  const _Float16* Kg = kcat + (size_t)bh * LQ * 128;
  const _Float16* Vg = vT + (size_t)bh * 64 * LQ;     // [dim][key]

  __shared__ _Float16 Ksh0[64 * 128];
  __shared__ _Float16 Ksh1[64 * 128];
  __shared__ _Float16 Vsh0[64 * 64];
  __shared__ _Float16 Vsh1[64 * 64];

  const int tid = threadIdx.x;
  const int w = tid >> 6;                    // wave 0..3
  const int lane = tid & 63;
  const int half = lane >> 5;                // 0/1
  const int l31 = lane & 31;

  const float lts = lam_ts[0], lst = lam_st[0], lss = lam_ss[0];

  // Q-combine into B-frags: wave w owns qrows qt0 + w*32 + [0,32)
  f16x8 qf[8];
#pragma unroll
  for (int db = 0; db < 4; ++db) {
    const _Float16* qp = &Qg[(size_t)(qt0 + w * 32 + l31) * 128 + db * 16 + half * 8];
    f16x8 a = *(const f16x8*)qp;          // qt dims
    f16x8 bq = *(const f16x8*)(qp + 64);  // qs dims
#pragma unroll
    for (int e = 0; e < 8; ++e) {
      float fa = (float)a[e], fb = (float)bq[e];
      qf[db][e]     = (_Float16)(QSCALE * (fa + lst * fb));
      qf[db + 4][e] = (_Float16)(QSCALE * (lts * fa + lss * fb));
    }
  }

  float m_i = -INFINITY;
  float l_i = 0.f;
  f32x16 O[2];
#pragma unroll
  for (int nt = 0; nt < 2; ++nt)
#pragma unroll
    for (int r = 0; r < 16; ++r) O[nt][r] = 0.f;

  auto dma = [&](int t, _Float16* Kd, _Float16* Vd) {
#pragma unroll
    for (int a = 0; a < 4; ++a) {
      int row = w * 16 + a * 4 + (lane >> 4);
      int sc = (lane & 15) ^ (row & 7);
      async_ld16(&Kg[(size_t)(t + row) * 128 + sc * 8], &Kd[(w * 16 + a * 4) * 128]);
    }
#pragma unroll
    for (int a = 0; a < 2; ++a) {
      int row = w * 16 + a * 8 + (lane >> 3);          // dim
      int sc = (lane & 7) ^ (row & 7);
      async_ld16(&Vg[(size_t)row * LQ + t + sc * 8], &Vd[(w * 16 + a * 8) * 64]);
    }
  };

  auto compute = [&](const _Float16* Ks, const _Float16* Vs) {
    // S^T[key][qrow]: 2 key-tiles of 32, contraction over 128 concat dims
    f32x16 S[2];
#pragma unroll
    for (int kb = 0; kb < 2; ++kb)
#pragma unroll
      for (int r = 0; r < 16; ++r) S[kb][r] = 0.f;
#pragma unroll
    for (int db = 0; db < 8; ++db) {
      const int pc = ((db * 2 + half) ^ (lane & 7)) * 8;
      f16x8 af[2];
#pragma unroll
      for (int kb = 0; kb < 2; ++kb)
        af[kb] = *(const f16x8*)&Ks[(kb * 32 + l31) * 128 + pc];
#pragma unroll
      for (int kb = 0; kb < 2; ++kb)
        S[kb] = __builtin_amdgcn_mfma_f32_32x32x16_f16(af[kb], qf[db], S[kb], 0, 0, 0);
    }

    // Online softmax (exp2 domain), lane-local qrow = l31.
    float mx = -INFINITY;
#pragma unroll
    for (int kb = 0; kb < 2; ++kb)
#pragma unroll
      for (int r = 0; r < 16; ++r) mx = fmaxf(mx, S[kb][r]);
    mx = fmaxf(mx, __shfl_xor(mx, 32));
    float m_new = fmaxf(m_i, mx);
    float alpha = __builtin_amdgcn_exp2f(m_i - m_new);
    float s = 0.f;
#pragma unroll
    for (int kb = 0; kb < 2; ++kb)
#pragma unroll
      for (int r = 0; r < 16; ++r) {
        float p = __builtin_amdgcn_exp2f(S[kb][r] - m_new);
        S[kb][r] = p;
        s += p;
      }
    s += __shfl_xor(s, 32);
    l_i = l_i * alpha + s;
    m_i = m_new;

    // Rescale O (lane-local alpha)
#pragma unroll
    for (int nt = 0; nt < 2; ++nt)
#pragma unroll
      for (int r = 0; r < 16; ++r) O[nt][r] *= alpha;

    // Pack P to f16 pairs: pu[kb][i] = (f16(S[2i]), f16(S[2i+1]))
    unsigned pu[2][8];
#pragma unroll
    for (int kb = 0; kb < 2; ++kb)
#pragma unroll
      for (int i = 0; i < 8; ++i) {
        f16x2 t2;
        t2[0] = (_Float16)S[kb][2 * i];
        t2[1] = (_Float16)S[kb][2 * i + 1];
        pu[kb][i] = __builtin_bit_cast(unsigned, t2);
      }

    // O^T += mfma(A=V^T, B=P^T). B-frag for key-block kb2=2*kb+c built by
    // half-exchange: lane needs keys kb2*16 + half*8 + j.
    //   j<4 values live in half-0 lanes (regs 8c+4*half_consumer+j ...):
    //   b[0:2) = half ? rcv_hi : own_lo ; b[2:4) = half ? own_hi : rcv_lo.
#pragma unroll
    for (int kb = 0; kb < 2; ++kb)
#pragma unroll
      for (int c = 0; c < 2; ++c) {
        unsigned ulo0 = pu[kb][4 * c + 0], ulo1 = pu[kb][4 * c + 1];
        unsigned uhi0 = pu[kb][4 * c + 2], uhi1 = pu[kb][4 * c + 3];
        unsigned rlo0 = (unsigned)__shfl_xor((int)ulo0, 32);
        unsigned rlo1 = (unsigned)__shfl_xor((int)ulo1, 32);
        unsigned rhi0 = (unsigned)__shfl_xor((int)uhi0, 32);
        unsigned rhi1 = (unsigned)__shfl_xor((int)uhi1, 32);
        union { unsigned u[4]; f16x8 v; } pb;
        pb.u[0] = half ? rhi0 : ulo0;
        pb.u[1] = half ? rhi1 : ulo1;
        pb.u[2] = half ? uhi0 : rlo0;
        pb.u[3] = half ? uhi1 : rlo1;
        int kb2 = kb * 2 + c;
        f16x8 av[2];
#pragma unroll
        for (int nt = 0; nt < 2; ++nt) {
          int dim = nt * 32 + l31;
          int pc = ((kb2 * 2 + half) ^ (dim & 7)) * 8;
          av[nt] = *(const f16x8*)&Vs[dim * 64 + pc];
        }
#pragma unroll
        for (int nt = 0; nt < 2; ++nt)
          O[nt] = __builtin_amdgcn_mfma_f32_32x32x16_f16(av[nt], pb.v, O[nt], 0, 0, 0);
      }
  };

  dma(0, Ksh0, Vsh0);
  for (int t = 0; t < LQ; t += 128) {
    __syncthreads();                 // drains DMA(t) + protects buffers
    dma(t + 64, Ksh1, Vsh1);         // overlaps with compute(t)
    compute(Ksh0, Vsh0);
    __syncthreads();                 // drains DMA(t+64)
    if (t + 128 < LQ) dma(t + 128, Ksh0, Vsh0);
    compute(Ksh1, Vsh1);
  }

  // Epilogue: lane-local 1/l; O^T row = dim, col = qrow (lane-local).
  float inv = 1.f / l_i;
  int qrow = qt0 + w * 32 + l31;
#pragma unroll
  for (int nt = 0; nt < 2; ++nt)
#pragma unroll
    for (int rg = 0; rg < 4; ++rg) {
      f16x4 o4;
#pragma unroll
      for (int i = 0; i < 4; ++i) o4[i] = (_Float16)(O[nt][rg * 4 + i] * inv);
      int dim = nt * 32 + rg * 8 + half * 4;
      *(f16x4*)&y[((size_t)b * LQ + qrow) * EQ + h * 64 + dim] = o4;
    }
}

// ---------------------------------------------------------------------------
extern "C" void kernel_launch(void* const* d_in, const int* in_sizes, int n_in,
                              void* d_out, int out_size, void* d_ws, size_t ws_size,
                              hipStream_t stream) {
  const float* xt = (const float*)d_in[0];
  const float* xs = (const float*)d_in[1];
  const float* Wt = (const float*)d_in[2];
  const float* bt = (const float*)d_in[3];
  const float* Ws = (const float*)d_in[4];
  const float* bs = (const float*)d_in[5];
  const float* Wc = (const float*)d_in[6];
  const float* bc = (const float*)d_in[7];
  const float* lam_ts = (const float*)d_in[8];
  const float* lam_st = (const float*)d_in[9];
  const float* lam_ss = (const float*)d_in[10];
  float* out = (float*)d_out;

  _Float16* w16 = (_Float16*)d_ws;
  _Float16* xt16 = w16;                       // 4,194,304
  _Float16* xs16 = xt16 + 4194304;            // 4,194,304
  _Float16* WtT  = xs16 + 4194304;            // 3,145,728
  _Float16* WsT  = WtT + 3145728;             // 2,097,152
  _Float16* WcT  = WsT + 2097152;             // 1,048,576
  _Float16* qcat = WcT + 1048576;             // 8,388,608  [bh][l][128] = [qt|qs]
  _Float16* kcat = qcat + 8388608;            // 8,388,608  [bh][l][128] = [kt|ks]
  _Float16* vbufT = kcat + 8388608;           // 4,194,304  [bh][dim][l]
  _Float16* ybuf = vbufT + 4194304;           // 4,194,304  [b*l][1024]

  prep<<<10240, 256, 0, stream>>>(xt, xs, Wt, Ws, Wc, xt16, xs16, WtT, WsT, WcT);
  proj_gemm<<<dim3(16, 80), 256, 0, stream>>>(
      xt16, xs16, WtT, WsT, bt, bs, qcat, kcat, vbufT);
  flash_attn_mfma<<<dim3(16, 32), 256, 0, stream>>>(
      qcat, kcat, vbufT, ybuf, lam_ts, lam_st, lam_ss);
  cproj_gemm<<<dim3(8, 32), 256, 0, stream>>>(ybuf, WcT, bc, out);
}

// Round 8
// 279.364 us; speedup vs baseline: 1.1024x; 1.0089x over previous
//
#include <hip/hip_runtime.h>
#include <math.h>

// Problem constants: B=2, L=2048, E=1024, H=16, D=64
#define LQ 2048
#define EQ 1024
#define M_ROWS 4096
#define BH 32

typedef _Float16 f16x8 __attribute__((ext_vector_type(8)));
typedef _Float16 f16x4 __attribute__((ext_vector_type(4)));
typedef _Float16 f16x2 __attribute__((ext_vector_type(2)));
typedef float f32x4 __attribute__((ext_vector_type(4)));
typedef float f32x16 __attribute__((ext_vector_type(16)));

// 1/sqrt(64) * log2(e) -> softmax in exp2 domain (applied to combined q)
#define QSCALE 0.1803368801111204f

__device__ __forceinline__ void async_ld16(const _Float16* g, _Float16* l) {
  __builtin_amdgcn_global_load_lds(
      (const __attribute__((address_space(1))) unsigned int*)g,
      (__attribute__((address_space(3))) unsigned int*)l, 16, 0, 0);
}

// ---------------------------------------------------------------------------
// Prep (1 launch): blocks [0,4096) convert xt,xs fp32->fp16;
// blocks [4096,10240) transpose W fp32[k][n] -> WT fp16[n][k].
// ---------------------------------------------------------------------------
__global__ __launch_bounds__(256) void prep(
    const float* __restrict__ xt, const float* __restrict__ xs,
    const float* __restrict__ Wt, const float* __restrict__ Ws,
    const float* __restrict__ Wc,
    _Float16* __restrict__ xt16, _Float16* __restrict__ xs16,
    _Float16* __restrict__ WtT, _Float16* __restrict__ WsT,
    _Float16* __restrict__ WcT) {
  int gb = blockIdx.x;
  if (gb < 4096) {
    int i = gb * 256 + threadIdx.x;
    const float* s; _Float16* d; size_t off;
    if (i < 524288) { s = xt; d = xt16; off = (size_t)i * 8; }
    else            { s = xs; d = xs16; off = (size_t)(i - 524288) * 8; }
    float4 a = *(const float4*)&s[off];
    float4 b = *(const float4*)&s[off + 4];
    f16x8 h;
    h[0] = (_Float16)a.x; h[1] = (_Float16)a.y; h[2] = (_Float16)a.z; h[3] = (_Float16)a.w;
    h[4] = (_Float16)b.x; h[5] = (_Float16)b.y; h[6] = (_Float16)b.z; h[7] = (_Float16)b.w;
    *(f16x8*)&d[off] = h;
  } else {
    __shared__ float T[32][33];
    int tb = gb - 4096;
    int tx = threadIdx.x & 31, ty = threadIdx.x >> 5;
    int c0 = (tb % 192) * 32;
    int k0 = (tb / 192) * 32;
    const float* W; _Float16* D; int Nw, cl;
    if (c0 < 3072)      { W = Wt; D = WtT; Nw = 3072; cl = c0; }
    else if (c0 < 5120) { W = Ws; D = WsT; Nw = 2048; cl = c0 - 3072; }
    else                { W = Wc; D = WcT; Nw = 1024; cl = c0 - 5120; }
#pragma unroll
    for (int j = 0; j < 4; ++j)
      T[ty + j * 8][tx] = W[(size_t)(k0 + ty + j * 8) * Nw + cl + tx];
    __syncthreads();
#pragma unroll
    for (int j = 0; j < 4; ++j)
      D[(size_t)(cl + ty + j * 8) * 1024 + k0 + tx] = (_Float16)T[tx][ty + j * 8];
  }
}

// ---------------------------------------------------------------------------
// Merged projection GEMM, DOUBLE-BUFFERED K-loop. Grid (16, 80):
//  by in [0,32):  t-QK -> qt->qcat[:,0:64], kt->kcat[:,0:64]
//  by in [32,48): V^T  -> vT[bh][d][l] contiguous along l
//  by in [48,80): s-QK -> qs->qcat[:,64:128], ks->kcat[:,64:128]
// Prefetch k-tile i+1 before computing tile i: barrier vmcnt drain has a
// full compute phase of slack; barrier count halves.
// LDS: 2 x (8K A + 8K B) = 32 KB.
// ---------------------------------------------------------------------------
__global__ __launch_bounds__(256) void proj_gemm(
    const _Float16* __restrict__ xt16, const _Float16* __restrict__ xs16,
    const _Float16* __restrict__ WtT, const _Float16* __restrict__ WsT,
    const float* __restrict__ bt, const float* __restrict__ bs,
    _Float16* __restrict__ q16, _Float16* __restrict__ k16,
    _Float16* __restrict__ v16) {
  __shared__ _Float16 Al0[128 * 32];
  __shared__ _Float16 Bl0[128 * 32];
  __shared__ _Float16 Al1[128 * 32];
  __shared__ _Float16 Bl1[128 * 32];

  const int tid = threadIdx.x;
  const int w = tid >> 6;
  const int lane = tid & 63;
  const int quad = lane >> 4;
  const int l15 = lane & 15;
  const int wm = w >> 1, wn = w & 1;
  const int by = blockIdx.y;
  const int n0 = blockIdx.x * 128;

  const _Float16* Ab;
  const _Float16* Bb;
  const float* bias;
  int m0, bsel = 0, branch;
  if (by < 32) {            // t-QK
    branch = 0; Ab = xt16; Bb = WtT; bias = bt; m0 = by * 128;
  } else if (by < 48) {     // V^T
    branch = 1;
    int by2 = by - 32;
    bsel = by2 >> 3;
    m0 = (by2 & 7) * 128;
    Ab = WtT + (size_t)2048 * 1024;
    Bb = xt16 + (size_t)bsel * 2048 * 1024;
    bias = bt;
  } else {                  // s-QK
    branch = 2; Ab = xs16; Bb = WsT; bias = bs; m0 = (by - 48) * 128;
  }

  const int srow = lane >> 2;
  const int schunk = ((lane & 3) ^ ((lane >> 3) & 3)) * 8;

  f32x4 acc[4][4];
#pragma unroll
  for (int mb = 0; mb < 4; ++mb)
#pragma unroll
    for (int nb = 0; nb < 4; ++nb) acc[mb][nb] = (f32x4){0.f, 0.f, 0.f, 0.f};

  const int key = (l15 >> 1) & 3;

  auto dma = [&](int kt, _Float16* Al, _Float16* Bl) {
#pragma unroll
    for (int i = 0; i < 2; ++i) {
      int rt = w * 32 + i * 16;
      async_ld16(&Ab[(size_t)(m0 + rt + srow) * 1024 + kt + schunk], &Al[rt * 32]);
      async_ld16(&Bb[(size_t)(n0 + rt + srow) * 1024 + kt + schunk], &Bl[rt * 32]);
    }
  };

  auto comp = [&](const _Float16* Al, const _Float16* Bl) {
    f16x8 af[4], bf[4];
    const int pc = (quad ^ key) * 8;
#pragma unroll
    for (int mb = 0; mb < 4; ++mb)
      af[mb] = *(const f16x8*)&Al[(wm * 64 + mb * 16 + l15) * 32 + pc];
#pragma unroll
    for (int nb = 0; nb < 4; ++nb)
      bf[nb] = *(const f16x8*)&Bl[(wn * 64 + nb * 16 + l15) * 32 + pc];
#pragma unroll
    for (int mb = 0; mb < 4; ++mb)
#pragma unroll
      for (int nb = 0; nb < 4; ++nb)
        acc[mb][nb] = __builtin_amdgcn_mfma_f32_16x16x32_f16(af[mb], bf[nb], acc[mb][nb], 0, 0, 0);
  };

  dma(0, Al0, Bl0);
  for (int kt = 0; kt < 1024; kt += 64) {
    __syncthreads();                       // drains dma(kt)
    dma(kt + 32, Al1, Bl1);                // prefetch, hidden under comp
    comp(Al0, Bl0);
    __syncthreads();                       // drains dma(kt+32)
    if (kt + 64 < 1024) dma(kt + 64, Al0, Bl0);
    comp(Al1, Bl1);
  }

#pragma unroll
  for (int mb = 0; mb < 4; ++mb)
#pragma unroll
    for (int nb = 0; nb < 4; ++nb)
#pragma unroll
      for (int r = 0; r < 4; ++r) {
        int row = m0 + wm * 64 + mb * 16 + quad * 4 + r;
        int col = n0 + wn * 64 + nb * 16 + l15;
        if (branch == 1) {
          float val = acc[mb][nb][r] + bias[2048 + row];
          v16[(size_t)(bsel * 1024 + row) * 2048 + col] = (_Float16)val;
        } else {
          float val = acc[mb][nb][r] + bias[col];
          int bb = row >> 11, ll = row & 2047;
          int which = col >> 10, e = col & 1023;
          int hh = e >> 6, dd = e & 63;
          size_t rowhd = (size_t)(bb * 16 + hh) * 2048 + ll;
          int off = (branch == 0) ? 0 : 64;
          if (which == 0) q16[rowhd * 128 + off + dd] = (_Float16)val;
          else            k16[rowhd * 128 + off + dd] = (_Float16)val;
        }
      }
}

// ---------------------------------------------------------------------------
// c_proj GEMM: out = ybuf @ WcT^T + bc, fp32 out. Tile 128x64, grid (16,32)
// = 512 blocks (2/CU), double-buffered. Waves 2x2; wave-tile 64x32 (4x2).
// LDS: 2 x (8K A + 4K B) = 24 KB.
// ---------------------------------------------------------------------------
__global__ __launch_bounds__(256) void cproj_gemm(
    const _Float16* __restrict__ A, const _Float16* __restrict__ Bm,
    const float* __restrict__ bias, float* __restrict__ outf) {
  __shared__ _Float16 Al0[128 * 32];
  __shared__ _Float16 Bl0[64 * 32];
  __shared__ _Float16 Al1[128 * 32];
  __shared__ _Float16 Bl1[64 * 32];

  const int tid = threadIdx.x;
  const int w = tid >> 6;
  const int lane = tid & 63;
  const int quad = lane >> 4;
  const int l15 = lane & 15;
  const int wm = w >> 1, wn = w & 1;
  const int m0 = blockIdx.y * 128;
  const int n0 = blockIdx.x * 64;

  const int srow = lane >> 2;
  const int schunk = ((lane & 3) ^ ((lane >> 3) & 3)) * 8;

  f32x4 acc[4][2];
#pragma unroll
  for (int mb = 0; mb < 4; ++mb)
#pragma unroll
    for (int nb = 0; nb < 2; ++nb) acc[mb][nb] = (f32x4){0.f, 0.f, 0.f, 0.f};

  const int key = (l15 >> 1) & 3;

  auto dma = [&](int kt, _Float16* Al, _Float16* Bl) {
#pragma unroll
    for (int i = 0; i < 2; ++i) {
      int rt = w * 32 + i * 16;
      async_ld16(&A[(size_t)(m0 + rt + srow) * 1024 + kt + schunk], &Al[rt * 32]);
    }
    int rtb = w * 16;
    async_ld16(&Bm[(size_t)(n0 + rtb + srow) * 1024 + kt + schunk], &Bl[rtb * 32]);
  };

  auto comp = [&](const _Float16* Al, const _Float16* Bl) {
    f16x8 af[4], bf[2];
    const int pc = (quad ^ key) * 8;
#pragma unroll
    for (int mb = 0; mb < 4; ++mb)
      af[mb] = *(const f16x8*)&Al[(wm * 64 + mb * 16 + l15) * 32 + pc];
#pragma unroll
    for (int nb = 0; nb < 2; ++nb)
      bf[nb] = *(const f16x8*)&Bl[(wn * 32 + nb * 16 + l15) * 32 + pc];
#pragma unroll
    for (int mb = 0; mb < 4; ++mb)
#pragma unroll
      for (int nb = 0; nb < 2; ++nb)
        acc[mb][nb] = __builtin_amdgcn_mfma_f32_16x16x32_f16(af[mb], bf[nb], acc[mb][nb], 0, 0, 0);
  };

  dma(0, Al0, Bl0);
  for (int kt = 0; kt < 1024; kt += 64) {
    __syncthreads();
    dma(kt + 32, Al1, Bl1);
    comp(Al0, Bl0);
    __syncthreads();
    if (kt + 64 < 1024) dma(kt + 64, Al0, Bl0);
    comp(Al1, Bl1);
  }

#pragma unroll
  for (int mb = 0; mb < 4; ++mb)
#pragma unroll
    for (int nb = 0; nb < 2; ++nb)
#pragma unroll
      for (int r = 0; r < 4; ++r) {
        int row = m0 + wm * 64 + mb * 16 + quad * 4 + r;
        int col = n0 + wn * 32 + nb * 16 + l15;
        outf[(size_t)row * 1024 + col] = acc[mb][nb][r] + bias[col];
      }
}

// ---------------------------------------------------------------------------
// MFMA flash attention v5 (unchanged from R7, verified): 32x32x16, O^T form,
// dbuf K/V DMA, q-combine on load, P via shfl_xor(32) register exchange.
// ---------------------------------------------------------------------------
__global__ __launch_bounds__(256, 2) void flash_attn_mfma(
    const _Float16* __restrict__ qcat, const _Float16* __restrict__ kcat,
    const _Float16* __restrict__ vT, _Float16* __restrict__ y,
    const float* __restrict__ lam_ts, const float* __restrict__ lam_st,
    const float* __restrict__ lam_ss) {
  const int bh = blockIdx.y;
  const int qt0 = blockIdx.x * 128;
  const int b = bh >> 4, h = bh & 15;
  const _Float16* Qg = qcat + (size_t)bh * LQ * 128;
  const _Float16* Kg = kcat + (size_t)bh * LQ * 128;
  const _Float16* Vg = vT + (size_t)bh * 64 * LQ;     // [dim][key]

  __shared__ _Float16 Ksh0[64 * 128];
  __shared__ _Float16 Ksh1[64 * 128];
  __shared__ _Float16 Vsh0[64 * 64];
  __shared__ _Float16 Vsh1[64 * 64];

  const int tid = threadIdx.x;
  const int w = tid >> 6;                    // wave 0..3
  const int lane = tid & 63;
  const int half = lane >> 5;                // 0/1
  const int l31 = lane & 31;

  const float lts = lam_ts[0], lst = lam_st[0], lss = lam_ss[0];

  // Q-combine into B-frags: wave w owns qrows qt0 + w*32 + [0,32)
  f16x8 qf[8];
#pragma unroll
  for (int db = 0; db < 4; ++db) {
    const _Float16* qp = &Qg[(size_t)(qt0 + w * 32 + l31) * 128 + db * 16 + half * 8];
    f16x8 a = *(const f16x8*)qp;          // qt dims
    f16x8 bq = *(const f16x8*)(qp + 64);  // qs dims
#pragma unroll
    for (int e = 0; e < 8; ++e) {
      float fa = (float)a[e], fb = (float)bq[e];
      qf[db][e]     = (_Float16)(QSCALE * (fa + lst * fb));
      qf[db + 4][e] = (_Float16)(QSCALE * (lts * fa + lss * fb));
    }
  }

  float m_i = -INFINITY;
  float l_i = 0.f;
  f32x16 O[2];
#pragma unroll
  for (int nt = 0; nt < 2; ++nt)
#pragma unroll
    for (int r = 0; r < 16; ++r) O[nt][r] = 0.f;

  auto dma = [&](int t, _Float16* Kd, _Float16* Vd) {
#pragma unroll
    for (int a = 0; a < 4; ++a) {
      int row = w * 16 + a * 4 + (lane >> 4);
      int sc = (lane & 15) ^ (row & 7);
      async_ld16(&Kg[(size_t)(t + row) * 128 + sc * 8], &Kd[(w * 16 + a * 4) * 128]);
    }
#pragma unroll
    for (int a = 0; a < 2; ++a) {
      int row = w * 16 + a * 8 + (lane >> 3);          // dim
      int sc = (lane & 7) ^ (row & 7);
      async_ld16(&Vg[(size_t)row * LQ + t + sc * 8], &Vd[(w * 16 + a * 8) * 64]);
    }
  };

  auto compute = [&](const _Float16* Ks, const _Float16* Vs) {
    f32x16 S[2];
#pragma unroll
    for (int kb = 0; kb < 2; ++kb)
#pragma unroll
      for (int r = 0; r < 16; ++r) S[kb][r] = 0.f;
#pragma unroll
    for (int db = 0; db < 8; ++db) {
      const int pc = ((db * 2 + half) ^ (lane & 7)) * 8;
      f16x8 af[2];
#pragma unroll
      for (int kb = 0; kb < 2; ++kb)
        af[kb] = *(const f16x8*)&Ks[(kb * 32 + l31) * 128 + pc];
#pragma unroll
      for (int kb = 0; kb < 2; ++kb)
        S[kb] = __builtin_amdgcn_mfma_f32_32x32x16_f16(af[kb], qf[db], S[kb], 0, 0, 0);
    }

    float mx = -INFINITY;
#pragma unroll
    for (int kb = 0; kb < 2; ++kb)
#pragma unroll
      for (int r = 0; r < 16; ++r) mx = fmaxf(mx, S[kb][r]);
    mx = fmaxf(mx, __shfl_xor(mx, 32));
    float m_new = fmaxf(m_i, mx);
    float alpha = __builtin_amdgcn_exp2f(m_i - m_new);
    float s = 0.f;
#pragma unroll
    for (int kb = 0; kb < 2; ++kb)
#pragma unroll
      for (int r = 0; r < 16; ++r) {
        float p = __builtin_amdgcn_exp2f(S[kb][r] - m_new);
        S[kb][r] = p;
        s += p;
      }
    s += __shfl_xor(s, 32);
    l_i = l_i * alpha + s;
    m_i = m_new;

#pragma unroll
    for (int nt = 0; nt < 2; ++nt)
#pragma unroll
      for (int r = 0; r < 16; ++r) O[nt][r] *= alpha;

    unsigned pu[2][8];
#pragma unroll
    for (int kb = 0; kb < 2; ++kb)
#pragma unroll
      for (int i = 0; i < 8; ++i) {
        f16x2 t2;
        t2[0] = (_Float16)S[kb][2 * i];
        t2[1] = (_Float16)S[kb][2 * i + 1];
        pu[kb][i] = __builtin_bit_cast(unsigned, t2);
      }

#pragma unroll
    for (int kb = 0; kb < 2; ++kb)
#pragma unroll
      for (int c = 0; c < 2; ++c) {
        unsigned ulo0 = pu[kb][4 * c + 0], ulo1 = pu[kb][4 * c + 1];
        unsigned uhi0 = pu[kb][4 * c + 2], uhi1 = pu[kb][4 * c + 3];
        unsigned rlo0 = (unsigned)__shfl_xor((int)ulo0, 32);
        unsigned rlo1 = (unsigned)__shfl_xor((int)ulo1, 32);
        unsigned rhi0 = (unsigned)__shfl_xor((int)uhi0, 32);
        unsigned rhi1 = (unsigned)__shfl_xor((int)uhi1, 32);
        union { unsigned u[4]; f16x8 v; } pb;
        pb.u[0] = half ? rhi0 : ulo0;
        pb.u[1] = half ? rhi1 : ulo1;
        pb.u[2] = half ? uhi0 : rlo0;
        pb.u[3] = half ? uhi1 : rlo1;
        int kb2 = kb * 2 + c;
        f16x8 av[2];
#pragma unroll
        for (int nt = 0; nt < 2; ++nt) {
          int dim = nt * 32 + l31;
          int pc = ((kb2 * 2 + half) ^ (dim & 7)) * 8;
          av[nt] = *(const f16x8*)&Vs[dim * 64 + pc];
        }
#pragma unroll
        for (int nt = 0; nt < 2; ++nt)
          O[nt] = __builtin_amdgcn_mfma_f32_32x32x16_f16(av[nt], pb.v, O[nt], 0, 0, 0);
      }
  };

  dma(0, Ksh0, Vsh0);
  for (int t = 0; t < LQ; t += 128) {
    __syncthreads();
    dma(t + 64, Ksh1, Vsh1);
    compute(Ksh0, Vsh0);
    __syncthreads();
    if (t + 128 < LQ) dma(t + 128, Ksh0, Vsh0);
    compute(Ksh1, Vsh1);
  }

  float inv = 1.f / l_i;
  int qrow = qt0 + w * 32 + l31;
#pragma unroll
  for (int nt = 0; nt < 2; ++nt)
#pragma unroll
    for (int rg = 0; rg < 4; ++rg) {
      f16x4 o4;
#pragma unroll
      for (int i = 0; i < 4; ++i) o4[i] = (_Float16)(O[nt][rg * 4 + i] * inv);
      int dim = nt * 32 + rg * 8 + half * 4;
      *(f16x4*)&y[((size_t)b * LQ + qrow) * EQ + h * 64 + dim] = o4;
    }
}

// ---------------------------------------------------------------------------
extern "C" void kernel_launch(void* const* d_in, const int* in_sizes, int n_in,
                              void* d_out, int out_size, void* d_ws, size_t ws_size,
                              hipStream_t stream) {
  const float* xt = (const float*)d_in[0];
  const float* xs = (const float*)d_in[1];
  const float* Wt = (const float*)d_in[2];
  const float* bt = (const float*)d_in[3];
  const float* Ws = (const float*)d_in[4];
  const float* bs = (const float*)d_in[5];
  const float* Wc = (const float*)d_in[6];
  const float* bc = (const float*)d_in[7];
  const float* lam_ts = (const float*)d_in[8];
  const float* lam_st = (const float*)d_in[9];
  const float* lam_ss = (const float*)d_in[10];
  float* out = (float*)d_out;

  _Float16* w16 = (_Float16*)d_ws;
  _Float16* xt16 = w16;                       // 4,194,304
  _Float16* xs16 = xt16 + 4194304;            // 4,194,304
  _Float16* WtT  = xs16 + 4194304;            // 3,145,728
  _Float16* WsT  = WtT + 3145728;             // 2,097,152
  _Float16* WcT  = WsT + 2097152;             // 1,048,576
  _Float16* qcat = WcT + 1048576;             // 8,388,608  [bh][l][128] = [qt|qs]
  _Float16* kcat = qcat + 8388608;            // 8,388,608  [bh][l][128] = [kt|ks]
  _Float16* vbufT = kcat + 8388608;           // 4,194,304  [bh][dim][l]
  _Float16* ybuf = vbufT + 4194304;           // 4,194,304  [b*l][1024]

  prep<<<10240, 256, 0, stream>>>(xt, xs, Wt, Ws, Wc, xt16, xs16, WtT, WsT, WcT);
  proj_gemm<<<dim3(16, 80), 256, 0, stream>>>(
      xt16, xs16, WtT, WsT, bt, bs, qcat, kcat, vbufT);
  flash_attn_mfma<<<dim3(16, 32), 256, 0, stream>>>(
      qcat, kcat, vbufT, ybuf, lam_ts, lam_st, lam_ss);
  cproj_gemm<<<dim3(16, 32), 256, 0, stream>>>(ybuf, WcT, bc, out);
}